// Round 1
// baseline (543.578 us; speedup 1.0000x reference)
//
#include <hip/hip_runtime.h>

#define NN 50000
#define NE 800000

static __device__ __forceinline__ float4 ld4(const float* p){ return *(const float4*)p; }

// ---------- counting sort by dst ----------
__global__ __launch_bounds__(256) void k_hist(const int* __restrict__ ei, int* __restrict__ cnt){
  int e = blockIdx.x*256 + threadIdx.x;
  if (e < NE) atomicAdd(&cnt[ei[NE + e]], 1);
}

__global__ __launch_bounds__(256) void k_scan1(const int* __restrict__ cnt, int* __restrict__ row_start, int* __restrict__ bsum){
  __shared__ int lds[256];
  int tid = threadIdx.x;
  int base = blockIdx.x*1024 + tid*4;
  int v0 = (base+0<NN)?cnt[base+0]:0;
  int v1 = (base+1<NN)?cnt[base+1]:0;
  int v2 = (base+2<NN)?cnt[base+2]:0;
  int v3 = (base+3<NN)?cnt[base+3]:0;
  int t = v0+v1+v2+v3;
  lds[tid] = t; __syncthreads();
  for (int off=1; off<256; off<<=1){
    int x = (tid>=off)? lds[tid-off] : 0;
    __syncthreads();
    lds[tid] += x;
    __syncthreads();
  }
  int excl = lds[tid] - t;
  int s0=excl+v0, s1=s0+v1, s2=s1+v2, s3=s2+v3;
  if (base+0<NN) row_start[base+1]=s0;
  if (base+1<NN) row_start[base+2]=s1;
  if (base+2<NN) row_start[base+3]=s2;
  if (base+3<NN) row_start[base+4]=s3;
  if (tid==255) bsum[blockIdx.x]=lds[255];
}

__global__ void k_scan2(const int* __restrict__ bsum, int* __restrict__ boff){
  __shared__ int lds[64];
  int t = threadIdx.x;
  int v = (t<49)? bsum[t] : 0;
  lds[t]=v; __syncthreads();
  for (int off=1; off<64; off<<=1){
    int x = (t>=off)? lds[t-off]:0;
    __syncthreads();
    lds[t]+=x;
    __syncthreads();
  }
  boff[t] = lds[t]-v;   // exclusive
}

__global__ __launch_bounds__(256) void k_scan3(int* __restrict__ row_start, const int* __restrict__ boff, int* __restrict__ cursor){
  int j = blockIdx.x*256 + threadIdx.x;
  if (j > NN) return;
  int rs = (j==0) ? 0 : row_start[j] + boff[(j-1)>>10];
  row_start[j] = rs;
  if (j < NN) cursor[j] = rs;
}

__global__ __launch_bounds__(256) void k_scatter(const int* __restrict__ ei, int* __restrict__ cursor, int2* __restrict__ sorted){
  int e = blockIdx.x*256 + threadIdx.x;
  if (e >= NE) return;
  int s = ei[e], d = ei[NE+e];
  int pos = atomicAdd(&cursor[d], 1);
  sorted[pos] = make_int2(s, e);
}

// ---------- phase A: per-dst sums of x[src] and edge_attr ----------
__global__ __launch_bounds__(256) void k_aggA(const int2* __restrict__ sorted, const int* __restrict__ row_start,
    const float* __restrict__ x, const float* __restrict__ ea,
    float* __restrict__ xs_agg, float* __restrict__ ea_agg){
  int v = blockIdx.x*4 + (threadIdx.x>>6);
  int lane = threadIdx.x & 63;
  if (v >= NN) return;
  int beg = row_start[v], end = row_start[v+1];
  float axs=0.f, aea=0.f;
  #pragma unroll 2
  for (int i=beg;i<end;i++){
    int2 se = sorted[i];
    axs += x[(size_t)se.x*64 + lane];
    aea += ea[(size_t)se.y*64 + lane];
  }
  xs_agg[(size_t)v*64+lane]=axs;
  ea_agg[(size_t)v*64+lane]=aea;
}

// ---------- layer-1 node GEMM ----------
__global__ __launch_bounds__(256) void k_gemm1(
  const float* __restrict__ xs_agg, const float* __restrict__ ea_agg, const float* __restrict__ x,
  const int* __restrict__ row_start,
  const float* __restrict__ W1m, const float* __restrict__ b1m,
  const float* __restrict__ W1e, const float* __restrict__ b1e,
  const float* __restrict__ W1s, const float* __restrict__ b1s,
  float* __restrict__ h)
{
  __shared__ float w_lds[32][260];
  __shared__ float in_lds[64][64];
  const int tid = threadIdx.x;
  const int vb = blockIdx.x*64;
  const int n = tid & 63, og = tid >> 6, o0 = og*16;
  const int v = vb + n;
  float acc[4][16];
  #pragma unroll
  for (int a=0;a<4;a++)
    #pragma unroll
    for (int b=0;b<16;b++) acc[a][b]=0.f;

  const float* ins[3] = {xs_agg, ea_agg, x};
  const float* Ws[3]  = {W1m, W1e, W1s};

  for (int s=0;s<3;s++){
    const float* src = ins[s];
    #pragma unroll
    for (int q=0;q<4;q++){
      int k = og*16 + q*4;
      float4 val = (v<NN)? ld4(src + (size_t)v*64 + k) : make_float4(0,0,0,0);
      in_lds[k+0][n]=val.x; in_lds[k+1][n]=val.y; in_lds[k+2][n]=val.z; in_lds[k+3][n]=val.w;
    }
    for (int kc=0;kc<2;kc++){
      const float* Wp = Ws[s] + (size_t)tid*64 + kc*32;
      #pragma unroll
      for (int q=0;q<8;q++){
        float4 w = ld4(Wp + q*4);
        int kk = q*4;
        w_lds[kk+0][tid]=w.x; w_lds[kk+1][tid]=w.y; w_lds[kk+2][tid]=w.z; w_lds[kk+3][tid]=w.w;
      }
      __syncthreads();
      #pragma unroll 2
      for (int kk=0;kk<32;kk++){
        float a = in_lds[kc*32+kk][n];
        #pragma unroll
        for (int oc=0;oc<4;oc++){
          const float* wr = &w_lds[kk][oc*64 + o0];
          float4 w0 = ld4(wr), w1 = ld4(wr+4), w2 = ld4(wr+8), w3 = ld4(wr+12);
          acc[oc][0] =fmaf(a,w0.x,acc[oc][0]);  acc[oc][1] =fmaf(a,w0.y,acc[oc][1]);
          acc[oc][2] =fmaf(a,w0.z,acc[oc][2]);  acc[oc][3] =fmaf(a,w0.w,acc[oc][3]);
          acc[oc][4] =fmaf(a,w1.x,acc[oc][4]);  acc[oc][5] =fmaf(a,w1.y,acc[oc][5]);
          acc[oc][6] =fmaf(a,w1.z,acc[oc][6]);  acc[oc][7] =fmaf(a,w1.w,acc[oc][7]);
          acc[oc][8] =fmaf(a,w2.x,acc[oc][8]);  acc[oc][9] =fmaf(a,w2.y,acc[oc][9]);
          acc[oc][10]=fmaf(a,w2.z,acc[oc][10]); acc[oc][11]=fmaf(a,w2.w,acc[oc][11]);
          acc[oc][12]=fmaf(a,w3.x,acc[oc][12]); acc[oc][13]=fmaf(a,w3.y,acc[oc][13]);
          acc[oc][14]=fmaf(a,w3.z,acc[oc][14]); acc[oc][15]=fmaf(a,w3.w,acc[oc][15]);
        }
      }
      __syncthreads();
    }
  }
  if (v < NN){
    float deg = (float)(row_start[v+1]-row_start[v]);
    float* hp = h + (size_t)v*256;
    #pragma unroll
    for (int oc=0;oc<4;oc++){
      #pragma unroll
      for (int g=0; g<4; g++){
        int ob = oc*64 + o0 + g*4;
        float4 r;
        r.x = acc[oc][g*4+0] + b1s[ob+0] + deg*(b1m[ob+0]+b1e[ob+0]);
        r.y = acc[oc][g*4+1] + b1s[ob+1] + deg*(b1m[ob+1]+b1e[ob+1]);
        r.z = acc[oc][g*4+2] + b1s[ob+2] + deg*(b1m[ob+2]+b1e[ob+2]);
        r.w = acc[oc][g*4+3] + b1s[ob+3] + deg*(b1m[ob+3]+b1e[ob+3]);
        r.x = fmaxf(r.x,0.f); r.y = fmaxf(r.y,0.f); r.z = fmaxf(r.z,0.f); r.w = fmaxf(r.w,0.f);
        *(float4*)(hp + ob) = r;
      }
    }
  }
}

// ---------- phase C: per-dst sum of h[src] (256-wide) ----------
__global__ __launch_bounds__(256) void k_aggC(const int2* __restrict__ sorted, const int* __restrict__ row_start,
    const float* __restrict__ h, float* __restrict__ hs){
  int v = blockIdx.x*4 + (threadIdx.x>>6);
  int lane = threadIdx.x & 63;
  if (v >= NN) return;
  int beg = row_start[v], end = row_start[v+1];
  float4 acc = make_float4(0,0,0,0);
  #pragma unroll 2
  for (int i=beg;i<end;i++){
    int s = sorted[i].x;
    float4 hv = ld4(h + (size_t)s*256 + lane*4);
    acc.x+=hv.x; acc.y+=hv.y; acc.z+=hv.z; acc.w+=hv.w;
  }
  *(float4*)(hs + (size_t)v*256 + lane*4) = acc;
}

// ---------- layer-2 node GEMM ----------
__global__ __launch_bounds__(256) void k_gemm2(
  const float* __restrict__ hs, const float* __restrict__ ea_agg, const float* __restrict__ h,
  const int* __restrict__ row_start,
  const float* __restrict__ W2m, const float* __restrict__ b2m,
  const float* __restrict__ W2e, const float* __restrict__ b2e,
  const float* __restrict__ W2s, const float* __restrict__ b2s,
  float* __restrict__ out)
{
  __shared__ float w_lds[64][68];
  __shared__ float in_lds[64][64];
  const int tid = threadIdx.x;
  const int vb = blockIdx.x*64;
  const int n = tid&63, og = tid>>6, o0 = og*16;
  const int v = vb+n;
  float acc[16];
  #pragma unroll
  for (int i=0;i<16;i++) acc[i]=0.f;

  #pragma unroll 1
  for (int c=0;c<9;c++){
    const float* inp; int ld; const float* Wp; int ldw; int koff;
    if (c<4){ inp=hs; ld=256; Wp=W2m; ldw=256; koff=c*64; }
    else if (c==4){ inp=ea_agg; ld=64; Wp=W2e; ldw=64; koff=0; }
    else { inp=h; ld=256; Wp=W2s; ldw=256; koff=(c-5)*64; }
    #pragma unroll
    for (int q=0;q<4;q++){
      int k = og*16+q*4;
      float4 val = (v<NN)? ld4(inp + (size_t)v*ld + koff + k) : make_float4(0,0,0,0);
      in_lds[k+0][n]=val.x; in_lds[k+1][n]=val.y; in_lds[k+2][n]=val.z; in_lds[k+3][n]=val.w;
      float4 w = ld4(Wp + (size_t)n*ldw + koff + k);
      w_lds[k+0][n]=w.x; w_lds[k+1][n]=w.y; w_lds[k+2][n]=w.z; w_lds[k+3][n]=w.w;
    }
    __syncthreads();
    #pragma unroll 4
    for (int k=0;k<64;k++){
      float a = in_lds[k][n];
      const float* wr = &w_lds[k][o0];
      float4 w0 = ld4(wr), w1 = ld4(wr+4), w2 = ld4(wr+8), w3 = ld4(wr+12);
      acc[0] =fmaf(a,w0.x,acc[0]);  acc[1] =fmaf(a,w0.y,acc[1]);
      acc[2] =fmaf(a,w0.z,acc[2]);  acc[3] =fmaf(a,w0.w,acc[3]);
      acc[4] =fmaf(a,w1.x,acc[4]);  acc[5] =fmaf(a,w1.y,acc[5]);
      acc[6] =fmaf(a,w1.z,acc[6]);  acc[7] =fmaf(a,w1.w,acc[7]);
      acc[8] =fmaf(a,w2.x,acc[8]);  acc[9] =fmaf(a,w2.y,acc[9]);
      acc[10]=fmaf(a,w2.z,acc[10]); acc[11]=fmaf(a,w2.w,acc[11]);
      acc[12]=fmaf(a,w3.x,acc[12]); acc[13]=fmaf(a,w3.y,acc[13]);
      acc[14]=fmaf(a,w3.z,acc[14]); acc[15]=fmaf(a,w3.w,acc[15]);
    }
    __syncthreads();
  }
  if (v<NN){
    float deg = (float)(row_start[v+1]-row_start[v]);
    float* op = out + (size_t)v*64;
    #pragma unroll
    for (int g=0; g<4; g++){
      int ob = o0 + g*4;
      float4 r;
      r.x = acc[g*4+0] + b2s[ob+0] + deg*(b2m[ob+0]+b2e[ob+0]);
      r.y = acc[g*4+1] + b2s[ob+1] + deg*(b2m[ob+1]+b2e[ob+1]);
      r.z = acc[g*4+2] + b2s[ob+2] + deg*(b2m[ob+2]+b2e[ob+2]);
      r.w = acc[g*4+3] + b2s[ob+3] + deg*(b2m[ob+3]+b2e[ob+3]);
      r.x = fmaxf(r.x,0.f); r.y = fmaxf(r.y,0.f); r.z = fmaxf(r.z,0.f); r.w = fmaxf(r.w,0.f);
      *(float4*)(op + ob) = r;
    }
  }
}

extern "C" void kernel_launch(void* const* d_in, const int* in_sizes, int n_in,
                              void* d_out, int out_size, void* d_ws, size_t ws_size,
                              hipStream_t stream){
  const float* x   = (const float*)d_in[0];
  const int*   ei  = (const int*)d_in[1];
  const float* ea  = (const float*)d_in[2];
  const float* W1m = (const float*)d_in[3];  const float* b1m = (const float*)d_in[4];
  const float* W1e = (const float*)d_in[5];  const float* b1e = (const float*)d_in[6];
  const float* W1s = (const float*)d_in[7];  const float* b1s = (const float*)d_in[8];
  const float* W2m = (const float*)d_in[9];  const float* b2m = (const float*)d_in[10];
  const float* W2e = (const float*)d_in[11]; const float* b2e = (const float*)d_in[12];
  const float* W2s = (const float*)d_in[13]; const float* b2s = (const float*)d_in[14];
  float* out = (float*)d_out;

  char* base = (char*)d_ws;
  size_t off = 0;
  auto alloc = [&](size_t bytes)->void* {
    void* r = base + off;
    off += (bytes + 255) & ~(size_t)255;
    return r;
  };
  int*   cc        = (int*)  alloc((size_t)NN*4);        // histogram, then cursor
  int*   row_start = (int*)  alloc((size_t)(NN+1)*4);
  int*   bsum      = (int*)  alloc(256);
  int*   boff      = (int*)  alloc(256);
  int2*  sorted    = (int2*) alloc((size_t)NE*8);
  float* ea_agg    = (float*)alloc((size_t)NN*64*4);
  float* h         = (float*)alloc((size_t)NN*256*4);
  float* hs        = (float*)alloc((size_t)NN*256*4);
  float* xs_agg    = hs;   // xs_agg dead before hs is written -> safe overlap

  hipMemsetAsync(cc, 0, (size_t)NN*4, stream);
  k_hist  <<<(NE+255)/256, 256, 0, stream>>>(ei, cc);
  k_scan1 <<<49, 256, 0, stream>>>(cc, row_start, bsum);
  k_scan2 <<<1, 64, 0, stream>>>(bsum, boff);
  k_scan3 <<<(NN+1+255)/256, 256, 0, stream>>>(row_start, boff, cc);
  k_scatter<<<(NE+255)/256, 256, 0, stream>>>(ei, cc, sorted);
  k_aggA  <<<(NN+3)/4, 256, 0, stream>>>(sorted, row_start, x, ea, xs_agg, ea_agg);
  k_gemm1 <<<(NN+63)/64, 256, 0, stream>>>(xs_agg, ea_agg, x, row_start,
                                           W1m,b1m,W1e,b1e,W1s,b1s, h);
  k_aggC  <<<(NN+3)/4, 256, 0, stream>>>(sorted, row_start, h, hs);
  k_gemm2 <<<(NN+63)/64, 256, 0, stream>>>(hs, ea_agg, h, row_start,
                                           W2m,b2m,W2e,b2e,W2s,b2s, out);
}

// Round 2
// 329.963 us; speedup vs baseline: 1.6474x; 1.6474x over previous
//
#include <hip/hip_runtime.h>

#define NN 50000
#define NE 800000

typedef float f32x4 __attribute__((ext_vector_type(4)));
typedef short short8 __attribute__((ext_vector_type(8)));

static __device__ __forceinline__ float4 ld4(const float* p){ return *(const float4*)p; }

static __device__ __forceinline__ unsigned short f2bf(float f){
  unsigned u = __builtin_bit_cast(unsigned, f);
  u = (u + 0x7fffu + ((u >> 16) & 1u)) >> 16;
  return (unsigned short)u;
}
static __device__ __forceinline__ float bf2f(unsigned short b){
  return __builtin_bit_cast(float, ((unsigned)b) << 16);
}

// ---------- counting sort by dst ----------
__global__ __launch_bounds__(256) void k_hist(const int* __restrict__ ei, int* __restrict__ cnt){
  int e = blockIdx.x*256 + threadIdx.x;
  if (e < NE) atomicAdd(&cnt[ei[NE + e]], 1);
}

__global__ __launch_bounds__(256) void k_scan1(const int* __restrict__ cnt, int* __restrict__ row_start, int* __restrict__ bsum){
  __shared__ int lds[256];
  int tid = threadIdx.x;
  int base = blockIdx.x*1024 + tid*4;
  int v0 = (base+0<NN)?cnt[base+0]:0;
  int v1 = (base+1<NN)?cnt[base+1]:0;
  int v2 = (base+2<NN)?cnt[base+2]:0;
  int v3 = (base+3<NN)?cnt[base+3]:0;
  int t = v0+v1+v2+v3;
  lds[tid] = t; __syncthreads();
  for (int off=1; off<256; off<<=1){
    int x = (tid>=off)? lds[tid-off] : 0;
    __syncthreads();
    lds[tid] += x;
    __syncthreads();
  }
  int excl = lds[tid] - t;
  int s0=excl+v0, s1=s0+v1, s2=s1+v2, s3=s2+v3;
  if (base+0<NN) row_start[base+1]=s0;
  if (base+1<NN) row_start[base+2]=s1;
  if (base+2<NN) row_start[base+3]=s2;
  if (base+3<NN) row_start[base+4]=s3;
  if (tid==255) bsum[blockIdx.x]=lds[255];
}

__global__ void k_scan2(const int* __restrict__ bsum, int* __restrict__ boff){
  __shared__ int lds[64];
  int t = threadIdx.x;
  int v = (t<49)? bsum[t] : 0;
  lds[t]=v; __syncthreads();
  for (int off=1; off<64; off<<=1){
    int x = (t>=off)? lds[t-off]:0;
    __syncthreads();
    lds[t]+=x;
    __syncthreads();
  }
  boff[t] = lds[t]-v;   // exclusive
}

__global__ __launch_bounds__(256) void k_scan3(int* __restrict__ row_start, const int* __restrict__ boff, int* __restrict__ cursor){
  int j = blockIdx.x*256 + threadIdx.x;
  if (j > NN) return;
  int rs = (j==0) ? 0 : row_start[j] + boff[(j-1)>>10];
  row_start[j] = rs;
  if (j < NN) cursor[j] = rs;
}

__global__ __launch_bounds__(256) void k_scatter(const int* __restrict__ ei, int* __restrict__ cursor, int2* __restrict__ sorted){
  int e = blockIdx.x*256 + threadIdx.x;
  if (e >= NE) return;
  int s = ei[e], d = ei[NE+e];
  int pos = atomicAdd(&cursor[d], 1);
  sorted[pos] = make_int2(s, e);
}

// ---------- prep: bf16 weight concat + bias folds + degree ----------
__global__ __launch_bounds__(256) void k_prep(
    const float* __restrict__ W1m, const float* __restrict__ b1m,
    const float* __restrict__ W1e, const float* __restrict__ b1e,
    const float* __restrict__ W1s, const float* __restrict__ b1s,
    const float* __restrict__ W2m, const float* __restrict__ b2m,
    const float* __restrict__ W2e, const float* __restrict__ b2e,
    const float* __restrict__ W2s, const float* __restrict__ b2s,
    const int* __restrict__ row_start,
    unsigned short* __restrict__ W1c, unsigned short* __restrict__ W2c,
    float* __restrict__ b1sA, float* __restrict__ b1dA,
    float* __restrict__ b2sA, float* __restrict__ b2dA,
    float* __restrict__ degf)
{
  int g = blockIdx.x*256 + threadIdx.x;
  if (g < 256*192){
    int oc = g/192, k = g%192;
    float w = (k<64)? W1m[oc*64+k] : (k<128)? W1e[oc*64+(k-64)] : W1s[oc*64+(k-128)];
    W1c[g] = f2bf(w);
  }
  if (g < 64*576){
    int oc = g/576, k = g%576;
    float w = (k<256)? W2m[oc*256+k] : (k<320)? W2e[oc*64+(k-256)] : W2s[oc*256+(k-320)];
    W2c[g] = f2bf(w);
  }
  if (g < 256){ b1sA[g] = b1s[g]; b1dA[g] = b1m[g] + b1e[g]; }
  if (g < 64) { b2sA[g] = b2s[g]; b2dA[g] = b2m[g] + b2e[g]; }
  if (g < NN) degf[g] = (float)(row_start[g+1] - row_start[g]);
}

// ---------- phase A: per-dst sums of x[src] and edge_attr -> bf16 in1 ----------
__global__ __launch_bounds__(256) void k_aggA(const int2* __restrict__ sorted, const int* __restrict__ row_start,
    const float* __restrict__ x, const float* __restrict__ ea,
    unsigned short* __restrict__ in1){
  int v = blockIdx.x*4 + (threadIdx.x>>6);
  int lane = threadIdx.x & 63;
  if (v >= NN) return;
  int beg = row_start[v], end = row_start[v+1];
  float axs=0.f, aea=0.f;
  #pragma unroll 2
  for (int i=beg;i<end;i++){
    int2 se = sorted[i];
    axs += x[(size_t)se.x*64 + lane];
    aea += ea[(size_t)se.y*64 + lane];
  }
  unsigned short* o = in1 + (size_t)v*192;
  o[lane]       = f2bf(axs);
  o[64 + lane]  = f2bf(aea);
  o[128 + lane] = f2bf(x[(size_t)v*64 + lane]);
}

// ---------- layer-1 MFMA GEMM: h = relu(in1 @ W1c^T + b1sA + deg*b1dA), bf16 out ----------
// block: 256 thr = 4 waves; block tile 64 nodes x 256 cols; wave w -> cols w*64..w*64+63
__global__ __launch_bounds__(256) void k_gemm1(
  const unsigned short* __restrict__ in1, const unsigned short* __restrict__ W1c,
  const float* __restrict__ b1sA, const float* __restrict__ b1dA,
  const float* __restrict__ degf, unsigned short* __restrict__ h)
{
  const int tid = threadIdx.x;
  const int w = tid >> 6, l = tid & 63;
  const int lrow = l & 15, lgrp = l >> 4;
  const int n0 = blockIdx.x * 64;
  const int c0 = w * 64;

  f32x4 acc[4][4];
  #pragma unroll
  for (int i=0;i<4;i++)
    #pragma unroll
    for (int j=0;j<4;j++) acc[i][j] = (f32x4)0.f;

  #pragma unroll 2
  for (int ks=0; ks<6; ks++){
    short8 a[4], b[4];
    #pragma unroll
    for (int rf=0; rf<4; rf++){
      int row = n0 + rf*16 + lrow; if (row >= NN) row = NN-1;
      a[rf] = *(const short8*)(in1 + row*192 + ks*32 + lgrp*8);
    }
    #pragma unroll
    for (int cf=0; cf<4; cf++){
      b[cf] = *(const short8*)(W1c + (c0 + cf*16 + lrow)*192 + ks*32 + lgrp*8);
    }
    #pragma unroll
    for (int rf=0; rf<4; rf++)
      #pragma unroll
      for (int cf=0; cf<4; cf++)
        acc[rf][cf] = __builtin_amdgcn_mfma_f32_16x16x32_bf16(a[rf], b[cf], acc[rf][cf], 0, 0, 0);
  }

  float dg[4][4];
  #pragma unroll
  for (int rf=0; rf<4; rf++)
    #pragma unroll
    for (int r=0; r<4; r++){
      int node = n0 + rf*16 + 4*lgrp + r;
      dg[rf][r] = (node < NN) ? degf[node] : 0.f;
    }

  #pragma unroll
  for (int cf=0; cf<4; cf++){
    int oc = c0 + cf*16 + lrow;
    float bs = b1sA[oc], bd = b1dA[oc];
    #pragma unroll
    for (int rf=0; rf<4; rf++){
      #pragma unroll
      for (int r=0; r<4; r++){
        int node = n0 + rf*16 + 4*lgrp + r;
        if (node < NN){
          float val = acc[rf][cf][r] + bs + dg[rf][r]*bd;
          val = fmaxf(val, 0.f);
          h[(size_t)node*256 + oc] = f2bf(val);
        }
      }
    }
  }
}

// ---------- phase C: per-dst sum of h[src] (bf16 rows, f32 accumulate) ----------
__global__ __launch_bounds__(256) void k_aggC(const int2* __restrict__ sorted, const int* __restrict__ row_start,
    const unsigned short* __restrict__ h, unsigned short* __restrict__ hs){
  int v = blockIdx.x*4 + (threadIdx.x>>6);
  int lane = threadIdx.x & 63;
  if (v >= NN) return;
  int beg = row_start[v], end = row_start[v+1];
  float a0=0.f, a1=0.f, a2=0.f, a3=0.f;
  #pragma unroll 2
  for (int i=beg;i<end;i++){
    int s = sorted[i].x;
    ushort4 hv = *(const ushort4*)(h + (size_t)s*256 + lane*4);
    a0 += bf2f(hv.x); a1 += bf2f(hv.y); a2 += bf2f(hv.z); a3 += bf2f(hv.w);
  }
  ushort4 o;
  o.x = f2bf(a0); o.y = f2bf(a1); o.z = f2bf(a2); o.w = f2bf(a3);
  *(ushort4*)(hs + (size_t)v*256 + lane*4) = o;
}

// ---------- layer-2 MFMA GEMM: out = relu([hs|ea|h] @ W2c^T + b2sA + deg*b2dA), f32 out ----------
// block: 256 thr = 4 waves; block tile 128 nodes x 64 cols; wave: (w>>1) row-half, (w&1) col-half (32 cols)
__global__ __launch_bounds__(256) void k_gemm2(
  const unsigned short* __restrict__ hs, const unsigned short* __restrict__ in1,
  const unsigned short* __restrict__ h,  const unsigned short* __restrict__ W2c,
  const float* __restrict__ b2sA, const float* __restrict__ b2dA,
  const float* __restrict__ degf, float* __restrict__ out)
{
  const int tid = threadIdx.x;
  const int w = tid >> 6, l = tid & 63;
  const int lrow = l & 15, lgrp = l >> 4;
  const int n0 = blockIdx.x * 128 + (w >> 1) * 64;
  const int c0 = (w & 1) * 32;

  f32x4 acc[4][2];
  #pragma unroll
  for (int i=0;i<4;i++){ acc[i][0] = (f32x4)0.f; acc[i][1] = (f32x4)0.f; }

  const unsigned short* segA[3] = { hs, in1 + 64, h };
  const int segLd[3]  = { 256, 192, 256 };
  const int segKs[3]  = { 8, 2, 8 };
  const int segWk[3]  = { 0, 256, 320 };

  #pragma unroll 1
  for (int sg=0; sg<3; sg++){
    const unsigned short* A = segA[sg];
    const int ld = segLd[sg], nks = segKs[sg], wk = segWk[sg];
    #pragma unroll 2
    for (int ks=0; ks<nks; ks++){
      short8 a[4], b[2];
      #pragma unroll
      for (int rf=0; rf<4; rf++){
        int row = n0 + rf*16 + lrow; if (row >= NN) row = NN-1;
        a[rf] = *(const short8*)(A + (size_t)row*ld + ks*32 + lgrp*8);
      }
      #pragma unroll
      for (int cf=0; cf<2; cf++){
        b[cf] = *(const short8*)(W2c + (c0 + cf*16 + lrow)*576 + wk + ks*32 + lgrp*8);
      }
      #pragma unroll
      for (int rf=0; rf<4; rf++)
        #pragma unroll
        for (int cf=0; cf<2; cf++)
          acc[rf][cf] = __builtin_amdgcn_mfma_f32_16x16x32_bf16(a[rf], b[cf], acc[rf][cf], 0, 0, 0);
    }
  }

  #pragma unroll
  for (int cf=0; cf<2; cf++){
    int oc = c0 + cf*16 + lrow;
    float bs = b2sA[oc], bd = b2dA[oc];
    #pragma unroll
    for (int rf=0; rf<4; rf++){
      #pragma unroll
      for (int r=0; r<4; r++){
        int node = n0 + rf*16 + 4*lgrp + r;
        if (node < NN){
          float val = acc[rf][cf][r] + bs + degf[node]*bd;
          out[(size_t)node*64 + oc] = fmaxf(val, 0.f);
        }
      }
    }
  }
}

extern "C" void kernel_launch(void* const* d_in, const int* in_sizes, int n_in,
                              void* d_out, int out_size, void* d_ws, size_t ws_size,
                              hipStream_t stream){
  const float* x   = (const float*)d_in[0];
  const int*   ei  = (const int*)d_in[1];
  const float* ea  = (const float*)d_in[2];
  const float* W1m = (const float*)d_in[3];  const float* b1m = (const float*)d_in[4];
  const float* W1e = (const float*)d_in[5];  const float* b1e = (const float*)d_in[6];
  const float* W1s = (const float*)d_in[7];  const float* b1s = (const float*)d_in[8];
  const float* W2m = (const float*)d_in[9];  const float* b2m = (const float*)d_in[10];
  const float* W2e = (const float*)d_in[11]; const float* b2e = (const float*)d_in[12];
  const float* W2s = (const float*)d_in[13]; const float* b2s = (const float*)d_in[14];
  float* out = (float*)d_out;

  char* base = (char*)d_ws;
  size_t off = 0;
  auto alloc = [&](size_t bytes)->void* {
    void* r = base + off;
    off += (bytes + 255) & ~(size_t)255;
    return r;
  };
  int*   cc        = (int*)  alloc((size_t)NN*4);        // histogram, then cursor
  int*   row_start = (int*)  alloc((size_t)(NN+1)*4);
  int*   bsum      = (int*)  alloc(256);
  int*   boff      = (int*)  alloc(256);
  int2*  sorted    = (int2*) alloc((size_t)NE*8);
  unsigned short* in1 = (unsigned short*)alloc((size_t)NN*192*2);  // [xs|ea|x] bf16
  unsigned short* h   = (unsigned short*)alloc((size_t)NN*256*2);
  unsigned short* hs  = (unsigned short*)alloc((size_t)NN*256*2);
  unsigned short* W1c = (unsigned short*)alloc((size_t)256*192*2);
  unsigned short* W2c = (unsigned short*)alloc((size_t)64*576*2);
  float* b1sA = (float*)alloc(256*4);
  float* b1dA = (float*)alloc(256*4);
  float* b2sA = (float*)alloc(64*4);
  float* b2dA = (float*)alloc(64*4);
  float* degf = (float*)alloc((size_t)NN*4);

  hipMemsetAsync(cc, 0, (size_t)NN*4, stream);
  k_hist   <<<(NE+255)/256, 256, 0, stream>>>(ei, cc);
  k_scan1  <<<49, 256, 0, stream>>>(cc, row_start, bsum);
  k_scan2  <<<1, 64, 0, stream>>>(bsum, boff);
  k_scan3  <<<(NN+1+255)/256, 256, 0, stream>>>(row_start, boff, cc);
  k_scatter<<<(NE+255)/256, 256, 0, stream>>>(ei, cc, sorted);
  k_prep   <<<(NN+255)/256, 256, 0, stream>>>(W1m,b1m,W1e,b1e,W1s,b1s,
                                              W2m,b2m,W2e,b2e,W2s,b2s,
                                              row_start, W1c, W2c,
                                              b1sA,b1dA,b2sA,b2dA, degf);
  k_aggA   <<<(NN+3)/4, 256, 0, stream>>>(sorted, row_start, x, ea, in1);
  k_gemm1  <<<(NN+63)/64, 256, 0, stream>>>(in1, W1c, b1sA, b1dA, degf, h);
  k_aggC   <<<(NN+3)/4, 256, 0, stream>>>(sorted, row_start, h, hs);
  k_gemm2  <<<(NN+127)/128, 256, 0, stream>>>(hs, in1, h, W2c, b2sA, b2dA, degf, out);
}

// Round 3
// 297.874 us; speedup vs baseline: 1.8249x; 1.1077x over previous
//
#include <hip/hip_runtime.h>

#define NN 50000
#define NE 800000

typedef float f32x4 __attribute__((ext_vector_type(4)));
typedef short short8 __attribute__((ext_vector_type(8)));

static __device__ __forceinline__ unsigned short f2bf(float f){
  unsigned u = __builtin_bit_cast(unsigned, f);
  u = (u + 0x7fffu + ((u >> 16) & 1u)) >> 16;
  return (unsigned short)u;
}
static __device__ __forceinline__ float bf2f(unsigned short b){
  return __builtin_bit_cast(float, ((unsigned)b) << 16);
}

// ---------- counting sort by dst ----------
__global__ __launch_bounds__(256) void k_hist(const int* __restrict__ ei, int* __restrict__ cnt){
  int e = blockIdx.x*256 + threadIdx.x;
  if (e < NE) atomicAdd(&cnt[ei[NE + e]], 1);
}

__global__ __launch_bounds__(256) void k_scan1(const int* __restrict__ cnt, int* __restrict__ row_start, int* __restrict__ bsum){
  __shared__ int lds[256];
  int tid = threadIdx.x;
  int base = blockIdx.x*1024 + tid*4;
  int v0 = (base+0<NN)?cnt[base+0]:0;
  int v1 = (base+1<NN)?cnt[base+1]:0;
  int v2 = (base+2<NN)?cnt[base+2]:0;
  int v3 = (base+3<NN)?cnt[base+3]:0;
  int t = v0+v1+v2+v3;
  lds[tid] = t; __syncthreads();
  for (int off=1; off<256; off<<=1){
    int x = (tid>=off)? lds[tid-off] : 0;
    __syncthreads();
    lds[tid] += x;
    __syncthreads();
  }
  int excl = lds[tid] - t;
  int s0=excl+v0, s1=s0+v1, s2=s1+v2, s3=s2+v3;
  if (base+0<NN) row_start[base+1]=s0;
  if (base+1<NN) row_start[base+2]=s1;
  if (base+2<NN) row_start[base+3]=s2;
  if (base+3<NN) row_start[base+4]=s3;
  if (tid==255) bsum[blockIdx.x]=lds[255];
}

__global__ void k_scan2(const int* __restrict__ bsum, int* __restrict__ boff){
  __shared__ int lds[64];
  int t = threadIdx.x;
  int v = (t<49)? bsum[t] : 0;
  lds[t]=v; __syncthreads();
  for (int off=1; off<64; off<<=1){
    int x = (t>=off)? lds[t-off]:0;
    __syncthreads();
    lds[t]+=x;
    __syncthreads();
  }
  boff[t] = lds[t]-v;   // exclusive
}

__global__ __launch_bounds__(256) void k_scan3(int* __restrict__ row_start, const int* __restrict__ boff, int* __restrict__ cursor){
  int j = blockIdx.x*256 + threadIdx.x;
  if (j > NN) return;
  int rs = (j==0) ? 0 : row_start[j] + boff[(j-1)>>10];
  row_start[j] = rs;
  if (j < NN) cursor[j] = rs;
}

__global__ __launch_bounds__(256) void k_scatter(const int* __restrict__ ei, int* __restrict__ cursor,
    int* __restrict__ srcs, int* __restrict__ eids){
  int e = blockIdx.x*256 + threadIdx.x;
  if (e >= NE) return;
  int s = ei[e], d = ei[NE+e];
  int pos = atomicAdd(&cursor[d], 1);
  srcs[pos] = s;
  eids[pos] = e;
}

// ---------- prep: bf16 weight concat + x->bf16 + bias folds + degree ----------
__global__ __launch_bounds__(256) void k_prep(
    const float* __restrict__ x,
    const float* __restrict__ W1m, const float* __restrict__ b1m,
    const float* __restrict__ W1e, const float* __restrict__ b1e,
    const float* __restrict__ W1s, const float* __restrict__ b1s,
    const float* __restrict__ W2m, const float* __restrict__ b2m,
    const float* __restrict__ W2e, const float* __restrict__ b2e,
    const float* __restrict__ W2s, const float* __restrict__ b2s,
    const int* __restrict__ row_start,
    unsigned short* __restrict__ xb,
    unsigned short* __restrict__ W1c, unsigned short* __restrict__ W2c,
    float* __restrict__ b1sA, float* __restrict__ b1dA,
    float* __restrict__ b2sA, float* __restrict__ b2dA,
    float* __restrict__ degf)
{
  int g = blockIdx.x*256 + threadIdx.x;
  if (g < NN*8){
    const float4* xp = (const float4*)x;
    float4 v0 = xp[(size_t)g*2], v1 = xp[(size_t)g*2+1];
    short8 o;
    o[0]=(short)f2bf(v0.x); o[1]=(short)f2bf(v0.y); o[2]=(short)f2bf(v0.z); o[3]=(short)f2bf(v0.w);
    o[4]=(short)f2bf(v1.x); o[5]=(short)f2bf(v1.y); o[6]=(short)f2bf(v1.z); o[7]=(short)f2bf(v1.w);
    *(short8*)(xb + (size_t)g*8) = o;
  }
  if (g < 256*192){
    int oc = g/192, k = g%192;
    float w = (k<64)? W1m[oc*64+k] : (k<128)? W1e[oc*64+(k-64)] : W1s[oc*64+(k-128)];
    W1c[g] = f2bf(w);
  }
  if (g < 64*576){
    int oc = g/576, k = g%576;
    float w = (k<256)? W2m[oc*256+k] : (k<320)? W2e[oc*64+(k-256)] : W2s[oc*256+(k-320)];
    W2c[g] = f2bf(w);
  }
  if (g < 256){ b1sA[g] = b1s[g]; b1dA[g] = b1m[g] + b1e[g]; }
  if (g < 64) { b2sA[g] = b2s[g]; b2dA[g] = b2m[g] + b2e[g]; }
  if (g < NN) degf[g] = (float)(row_start[g+1] - row_start[g]);
}

// ---------- phase A: per-dst sums of x[src] (bf16) and edge_attr (f32) -> bf16 in1 ----------
__global__ __launch_bounds__(256) void k_aggA(const int* __restrict__ srcs, const int* __restrict__ eids,
    const int* __restrict__ row_start,
    const unsigned short* __restrict__ xb, const float* __restrict__ ea,
    unsigned short* __restrict__ in1){
  int v = blockIdx.x*4 + (threadIdx.x>>6);
  int lane = threadIdx.x & 63;
  if (v >= NN) return;
  int beg = row_start[v], end = row_start[v+1];
  float xs0=0.f,xs1=0.f,xs2=0.f,xs3=0.f;
  float e0=0.f,e1=0.f,e2=0.f,e3=0.f;
  int i = beg;
  for (; i+4 <= end; i += 4){
    int s0=srcs[i+0], s1=srcs[i+1], s2=srcs[i+2], s3=srcs[i+3];
    int q0=eids[i+0], q1=eids[i+1], q2=eids[i+2], q3=eids[i+3];
    unsigned short h0 = xb[(size_t)s0*64+lane];
    unsigned short h1 = xb[(size_t)s1*64+lane];
    unsigned short h2 = xb[(size_t)s2*64+lane];
    unsigned short h3 = xb[(size_t)s3*64+lane];
    float f0 = ea[(size_t)q0*64+lane];
    float f1 = ea[(size_t)q1*64+lane];
    float f2 = ea[(size_t)q2*64+lane];
    float f3 = ea[(size_t)q3*64+lane];
    xs0 += bf2f(h0); xs1 += bf2f(h1); xs2 += bf2f(h2); xs3 += bf2f(h3);
    e0 += f0; e1 += f1; e2 += f2; e3 += f3;
  }
  for (; i < end; i++){
    xs0 += bf2f(xb[(size_t)srcs[i]*64+lane]);
    e0  += ea[(size_t)eids[i]*64+lane];
  }
  float axs = (xs0+xs1)+(xs2+xs3);
  float aea = (e0+e1)+(e2+e3);
  unsigned short* o = in1 + (size_t)v*192;
  o[lane]       = f2bf(axs);
  o[64 + lane]  = f2bf(aea);
  o[128 + lane] = xb[(size_t)v*64 + lane];
}

// ---------- layer-1 MFMA GEMM: h = relu(in1 @ W1c^T + b1sA + deg*b1dA), bf16 out ----------
__global__ __launch_bounds__(256) void k_gemm1(
  const unsigned short* __restrict__ in1, const unsigned short* __restrict__ W1c,
  const float* __restrict__ b1sA, const float* __restrict__ b1dA,
  const float* __restrict__ degf, unsigned short* __restrict__ h)
{
  const int tid = threadIdx.x;
  const int w = tid >> 6, l = tid & 63;
  const int lrow = l & 15, lgrp = l >> 4;
  const int n0 = blockIdx.x * 64;
  const int c0 = w * 64;

  f32x4 acc[4][4];
  #pragma unroll
  for (int i=0;i<4;i++)
    #pragma unroll
    for (int j=0;j<4;j++) acc[i][j] = (f32x4)0.f;

  #pragma unroll 2
  for (int ks=0; ks<6; ks++){
    short8 a[4], b[4];
    #pragma unroll
    for (int rf=0; rf<4; rf++){
      int row = n0 + rf*16 + lrow; if (row >= NN) row = NN-1;
      a[rf] = *(const short8*)(in1 + row*192 + ks*32 + lgrp*8);
    }
    #pragma unroll
    for (int cf=0; cf<4; cf++){
      b[cf] = *(const short8*)(W1c + (c0 + cf*16 + lrow)*192 + ks*32 + lgrp*8);
    }
    #pragma unroll
    for (int rf=0; rf<4; rf++)
      #pragma unroll
      for (int cf=0; cf<4; cf++)
        acc[rf][cf] = __builtin_amdgcn_mfma_f32_16x16x32_bf16(a[rf], b[cf], acc[rf][cf], 0, 0, 0);
  }

  float dg[4][4];
  #pragma unroll
  for (int rf=0; rf<4; rf++)
    #pragma unroll
    for (int r=0; r<4; r++){
      int node = n0 + rf*16 + 4*lgrp + r;
      dg[rf][r] = (node < NN) ? degf[node] : 0.f;
    }

  #pragma unroll
  for (int cf=0; cf<4; cf++){
    int oc = c0 + cf*16 + lrow;
    float bs = b1sA[oc], bd = b1dA[oc];
    #pragma unroll
    for (int rf=0; rf<4; rf++){
      #pragma unroll
      for (int r=0; r<4; r++){
        int node = n0 + rf*16 + 4*lgrp + r;
        if (node < NN){
          float val = acc[rf][cf][r] + bs + dg[rf][r]*bd;
          val = fmaxf(val, 0.f);
          h[(size_t)node*256 + oc] = f2bf(val);
        }
      }
    }
  }
}

// ---------- phase C: per-dst sum of h[src] (bf16 rows, f32 accumulate) ----------
__global__ __launch_bounds__(256) void k_aggC(const int* __restrict__ srcs, const int* __restrict__ row_start,
    const unsigned short* __restrict__ h, unsigned short* __restrict__ hs){
  int v = blockIdx.x*4 + (threadIdx.x>>6);
  int lane = threadIdx.x & 63;
  if (v >= NN) return;
  int beg = row_start[v], end = row_start[v+1];
  float a0[4]={0,0,0,0}, a1[4]={0,0,0,0}, a2[4]={0,0,0,0}, a3[4]={0,0,0,0};
  int i = beg;
  for (; i+4 <= end; i += 4){
    int s0=srcs[i+0], s1=srcs[i+1], s2=srcs[i+2], s3=srcs[i+3];
    ushort4 h0 = *(const ushort4*)(h + (size_t)s0*256 + lane*4);
    ushort4 h1 = *(const ushort4*)(h + (size_t)s1*256 + lane*4);
    ushort4 h2 = *(const ushort4*)(h + (size_t)s2*256 + lane*4);
    ushort4 h3 = *(const ushort4*)(h + (size_t)s3*256 + lane*4);
    a0[0]+=bf2f(h0.x); a0[1]+=bf2f(h0.y); a0[2]+=bf2f(h0.z); a0[3]+=bf2f(h0.w);
    a1[0]+=bf2f(h1.x); a1[1]+=bf2f(h1.y); a1[2]+=bf2f(h1.z); a1[3]+=bf2f(h1.w);
    a2[0]+=bf2f(h2.x); a2[1]+=bf2f(h2.y); a2[2]+=bf2f(h2.z); a2[3]+=bf2f(h2.w);
    a3[0]+=bf2f(h3.x); a3[1]+=bf2f(h3.y); a3[2]+=bf2f(h3.z); a3[3]+=bf2f(h3.w);
  }
  for (; i < end; i++){
    int s = srcs[i];
    ushort4 hv = *(const ushort4*)(h + (size_t)s*256 + lane*4);
    a0[0]+=bf2f(hv.x); a0[1]+=bf2f(hv.y); a0[2]+=bf2f(hv.z); a0[3]+=bf2f(hv.w);
  }
  ushort4 o;
  o.x = f2bf((a0[0]+a1[0])+(a2[0]+a3[0]));
  o.y = f2bf((a0[1]+a1[1])+(a2[1]+a3[1]));
  o.z = f2bf((a0[2]+a1[2])+(a2[2]+a3[2]));
  o.w = f2bf((a0[3]+a1[3])+(a2[3]+a3[3]));
  *(ushort4*)(hs + (size_t)v*256 + lane*4) = o;
}

// ---------- layer-2 MFMA GEMM: out = relu([hs|ea|h] @ W2c^T + b2sA + deg*b2dA), f32 out ----------
__global__ __launch_bounds__(256) void k_gemm2(
  const unsigned short* __restrict__ hs, const unsigned short* __restrict__ in1,
  const unsigned short* __restrict__ h,  const unsigned short* __restrict__ W2c,
  const float* __restrict__ b2sA, const float* __restrict__ b2dA,
  const float* __restrict__ degf, float* __restrict__ out)
{
  const int tid = threadIdx.x;
  const int w = tid >> 6, l = tid & 63;
  const int lrow = l & 15, lgrp = l >> 4;
  const int n0 = blockIdx.x * 128 + (w >> 1) * 64;
  const int c0 = (w & 1) * 32;

  f32x4 acc[4][2];
  #pragma unroll
  for (int i=0;i<4;i++){ acc[i][0] = (f32x4)0.f; acc[i][1] = (f32x4)0.f; }

  const unsigned short* segA[3] = { hs, in1 + 64, h };
  const int segLd[3]  = { 256, 192, 256 };
  const int segKs[3]  = { 8, 2, 8 };
  const int segWk[3]  = { 0, 256, 320 };

  #pragma unroll 1
  for (int sg=0; sg<3; sg++){
    const unsigned short* A = segA[sg];
    const int ld = segLd[sg], nks = segKs[sg], wk = segWk[sg];
    #pragma unroll 2
    for (int ks=0; ks<nks; ks++){
      short8 a[4], b[2];
      #pragma unroll
      for (int rf=0; rf<4; rf++){
        int row = n0 + rf*16 + lrow; if (row >= NN) row = NN-1;
        a[rf] = *(const short8*)(A + (size_t)row*ld + ks*32 + lgrp*8);
      }
      #pragma unroll
      for (int cf=0; cf<2; cf++){
        b[cf] = *(const short8*)(W2c + (c0 + cf*16 + lrow)*576 + wk + ks*32 + lgrp*8);
      }
      #pragma unroll
      for (int rf=0; rf<4; rf++)
        #pragma unroll
        for (int cf=0; cf<2; cf++)
          acc[rf][cf] = __builtin_amdgcn_mfma_f32_16x16x32_bf16(a[rf], b[cf], acc[rf][cf], 0, 0, 0);
    }
  }

  #pragma unroll
  for (int cf=0; cf<2; cf++){
    int oc = c0 + cf*16 + lrow;
    float bs = b2sA[oc], bd = b2dA[oc];
    #pragma unroll
    for (int rf=0; rf<4; rf++){
      #pragma unroll
      for (int r=0; r<4; r++){
        int node = n0 + rf*16 + 4*lgrp + r;
        if (node < NN){
          float val = acc[rf][cf][r] + bs + degf[node]*bd;
          out[(size_t)node*64 + oc] = fmaxf(val, 0.f);
        }
      }
    }
  }
}

extern "C" void kernel_launch(void* const* d_in, const int* in_sizes, int n_in,
                              void* d_out, int out_size, void* d_ws, size_t ws_size,
                              hipStream_t stream){
  const float* x   = (const float*)d_in[0];
  const int*   ei  = (const int*)d_in[1];
  const float* ea  = (const float*)d_in[2];
  const float* W1m = (const float*)d_in[3];  const float* b1m = (const float*)d_in[4];
  const float* W1e = (const float*)d_in[5];  const float* b1e = (const float*)d_in[6];
  const float* W1s = (const float*)d_in[7];  const float* b1s = (const float*)d_in[8];
  const float* W2m = (const float*)d_in[9];  const float* b2m = (const float*)d_in[10];
  const float* W2e = (const float*)d_in[11]; const float* b2e = (const float*)d_in[12];
  const float* W2s = (const float*)d_in[13]; const float* b2s = (const float*)d_in[14];
  float* out = (float*)d_out;

  char* base = (char*)d_ws;
  size_t off = 0;
  auto alloc = [&](size_t bytes)->void* {
    void* r = base + off;
    off += (bytes + 255) & ~(size_t)255;
    return r;
  };
  int*   cc        = (int*)  alloc((size_t)NN*4);        // histogram, then cursor
  int*   row_start = (int*)  alloc((size_t)(NN+1)*4);
  int*   bsum      = (int*)  alloc(256);
  int*   boff      = (int*)  alloc(256);
  int*   srcs      = (int*)  alloc((size_t)NE*4);
  int*   eids      = (int*)  alloc((size_t)NE*4);
  unsigned short* in1 = (unsigned short*)alloc((size_t)NN*192*2);  // [xs|ea|x] bf16
  unsigned short* h   = (unsigned short*)alloc((size_t)NN*256*2);
  unsigned short* hs  = (unsigned short*)alloc((size_t)NN*256*2);
  unsigned short* xb  = (unsigned short*)alloc((size_t)NN*64*2);
  unsigned short* W1c = (unsigned short*)alloc((size_t)256*192*2);
  unsigned short* W2c = (unsigned short*)alloc((size_t)64*576*2);
  float* b1sA = (float*)alloc(256*4);
  float* b1dA = (float*)alloc(256*4);
  float* b2sA = (float*)alloc(64*4);
  float* b2dA = (float*)alloc(64*4);
  float* degf = (float*)alloc((size_t)NN*4);

  hipMemsetAsync(cc, 0, (size_t)NN*4, stream);
  k_hist   <<<(NE+255)/256, 256, 0, stream>>>(ei, cc);
  k_scan1  <<<49, 256, 0, stream>>>(cc, row_start, bsum);
  k_scan2  <<<1, 64, 0, stream>>>(bsum, boff);
  k_scan3  <<<(NN+1+255)/256, 256, 0, stream>>>(row_start, boff, cc);
  k_scatter<<<(NE+255)/256, 256, 0, stream>>>(ei, cc, srcs, eids);
  k_prep   <<<(NN*8+255)/256, 256, 0, stream>>>(x, W1m,b1m,W1e,b1e,W1s,b1s,
                                              W2m,b2m,W2e,b2e,W2s,b2s,
                                              row_start, xb, W1c, W2c,
                                              b1sA,b1dA,b2sA,b2dA, degf);
  k_aggA   <<<(NN+3)/4, 256, 0, stream>>>(srcs, eids, row_start, xb, ea, in1);
  k_gemm1  <<<(NN+63)/64, 256, 0, stream>>>(in1, W1c, b1sA, b1dA, degf, h);
  k_aggC   <<<(NN+3)/4, 256, 0, stream>>>(srcs, row_start, h, hs);
  k_gemm2  <<<(NN+127)/128, 256, 0, stream>>>(hs, in1, h, W2c, b2sA, b2dA, degf, out);
}